// Round 3
// baseline (2150.438 us; speedup 1.0000x reference)
//
#include <hip/hip_runtime.h>

#define D_MODEL 768
#define D_INNER 1536
#define D_STATE 16
#define DT_RANK 96
#define BB 2
#define LL 2048
#define TT (BB*LL)          // 4096 tokens

typedef unsigned short u16;

__device__ __forceinline__ float bf2f(u16 u) {
    union { unsigned int i; float f; } c; c.i = ((unsigned int)u) << 16; return c.f;
}
__device__ __forceinline__ u16 f2bf(float f) {
    union { float f; unsigned int i; } c; c.f = f;
    unsigned int x = c.i;
    return (u16)((x + 0x7fffu + ((x >> 16) & 1u)) >> 16);   // RNE
}
// dtype-flex input loads: inputs are either fp32 (per reference) or bf16 (if harness converts)
__device__ __forceinline__ float ldx(const void* p, size_t i, bool f32) {
    return f32 ? ((const float*)p)[i] : bf2f(((const u16*)p)[i]);
}
__device__ __forceinline__ float4 ldx4(const void* p, size_t i, bool f32) {
    if (f32) return *(const float4*)((const float*)p + i);
    ushort4 q = *(const ushort4*)((const u16*)p + i);
    float4 r; r.x = bf2f(q.x); r.y = bf2f(q.y); r.z = bf2f(q.z); r.w = bf2f(q.w);
    return r;
}

// ---- dtype detect: if buffer is fp32, even-index u16s are mantissa-low garbage ----
__global__ void detect_kernel(const void* x, int* flag)
{
    __shared__ int bad;
    if (threadIdx.x == 0) bad = 0;
    __syncthreads();
    const u16* p = (const u16*)x;
    int local = 0;
    for (int i = threadIdx.x; i < 2048; i += 256) {
        const float v = bf2f(p[2 * i]);
        if (!(fabsf(v) < 1e4f)) local = 1;   // catches huge exponents AND NaN
    }
    if (local) atomicOr(&bad, 1);
    __syncthreads();
    if (threadIdx.x == 0) *flag = bad;       // 1 => inputs are fp32
}

// ---------------- LayerNorm: x (T,768) -> xn (T,768) bf16 ----------------
__global__ __launch_bounds__(256) void ln_kernel(const void* __restrict__ x,
    const void* __restrict__ g, const void* __restrict__ b, u16* __restrict__ xn,
    const int* __restrict__ flagp)
{
    const bool f32 = (*flagp != 0);
    const int tok = blockIdx.x;
    const int tid = threadIdx.x;
    const size_t base = (size_t)tok * D_MODEL;
    float v[3];
    v[0] = ldx(x, base + tid, f32);
    v[1] = ldx(x, base + tid + 256, f32);
    v[2] = ldx(x, base + tid + 512, f32);
    float s = v[0] + v[1] + v[2];
    float q = v[0]*v[0] + v[1]*v[1] + v[2]*v[2];
    #pragma unroll
    for (int o = 32; o > 0; o >>= 1) {
        s += __shfl_down(s, o, 64);
        q += __shfl_down(q, o, 64);
    }
    __shared__ float ss[4], qq[4];
    if ((tid & 63) == 0) { ss[tid >> 6] = s; qq[tid >> 6] = q; }
    __syncthreads();
    const float S = ss[0] + ss[1] + ss[2] + ss[3];
    const float Q = qq[0] + qq[1] + qq[2] + qq[3];
    const float mu  = S * (1.f / D_MODEL);
    const float var = Q * (1.f / D_MODEL) - mu * mu;
    const float rs  = rsqrtf(var + 1e-5f);
    u16* outr = xn + base;
    #pragma unroll
    for (int i = 0; i < 3; ++i) {
        const int c = tid + i * 256;
        outr[c] = f2bf((v[i] - mu) * rs * ldx(g, c, f32) + ldx(b, c, f32));
    }
}

// -- 64x64-tile GEMM: C = A(ws bf16) * B(input, flex dtype); fp32 acc --
// FINAL: add flex residual, store to flex-dtype output buffer.
template<bool FINAL>
__global__ __launch_bounds__(256) void gemm_kernel(
    const u16* __restrict__ A, const void* __restrict__ Bw,
    u16* __restrict__ C, void* __restrict__ Cout, const void* __restrict__ res,
    const int* __restrict__ flagp,
    int M, int N, int K, int lda, int ldb, int boff, int ldc)
{
    const bool f32 = (*flagp != 0);
    __shared__ __align__(16) float As[16][68];
    __shared__ __align__(16) float Bs[16][68];
    const int tid  = threadIdx.x;
    const int row0 = blockIdx.y * 64;
    const int col0 = blockIdx.x * 64;
    const int r0 = (tid >> 4) * 4;      // micro-tile rows
    const int c0 = (tid & 15) * 4;      // micro-tile cols
    const int a_row = tid >> 2;         // A tile: 64 rows x 16 k
    const int a_k   = (tid & 3) * 4;
    const int b_row = tid >> 4;         // B tile: 16 k x 64 cols
    const int b_col = (tid & 15) * 4;
    float acc[4][4] = {};
    for (int kt = 0; kt < K; kt += 16) {
        const ushort4 a4 = *(const ushort4*)(A + (size_t)(row0 + a_row) * lda + kt + a_k);
        const float4  b4 = ldx4(Bw, (size_t)(kt + b_row) * ldb + boff + col0 + b_col, f32);
        As[a_k + 0][a_row] = bf2f(a4.x);
        As[a_k + 1][a_row] = bf2f(a4.y);
        As[a_k + 2][a_row] = bf2f(a4.z);
        As[a_k + 3][a_row] = bf2f(a4.w);
        Bs[b_row][b_col + 0] = b4.x;
        Bs[b_row][b_col + 1] = b4.y;
        Bs[b_row][b_col + 2] = b4.z;
        Bs[b_row][b_col + 3] = b4.w;
        __syncthreads();
        #pragma unroll
        for (int k = 0; k < 16; ++k) {
            const float4 av = *(const float4*)(&As[k][r0]);
            const float4 bv = *(const float4*)(&Bs[k][c0]);
            const float aa[4] = {av.x, av.y, av.z, av.w};
            const float bb[4] = {bv.x, bv.y, bv.z, bv.w};
            #pragma unroll
            for (int i = 0; i < 4; ++i)
                #pragma unroll
                for (int j = 0; j < 4; ++j)
                    acc[i][j] += aa[i] * bb[j];
        }
        __syncthreads();
    }
    #pragma unroll
    for (int i = 0; i < 4; ++i) {
        const int row = row0 + r0 + i;
        #pragma unroll
        for (int j = 0; j < 4; ++j) {
            const int col = col0 + c0 + j;
            const size_t idx = (size_t)row * ldc + col;
            if (FINAL) {
                const float v = acc[i][j] + ldx(res, idx, f32);
                if (f32) ((float*)Cout)[idx] = v;
                else     ((u16*)Cout)[idx]   = f2bf(v);
            } else {
                C[idx] = f2bf(acc[i][j]);
            }
        }
    }
}

// ---- causal depthwise conv (width 4, left-pad 3) + SiLU: u (T,1536) -> us ----
__global__ __launch_bounds__(256) void conv_silu_kernel(
    const u16* __restrict__ u, const void* __restrict__ cw, const void* __restrict__ cb,
    u16* __restrict__ us, const int* __restrict__ flagp)
{
    const bool f32 = (*flagp != 0);
    const int idx = blockIdx.x * 256 + threadIdx.x;   // over T*D_INNER
    const int d   = idx % D_INNER;
    const int tok = idx / D_INNER;
    const int l   = tok & (LL - 1);
    float acc = ldx(cb, d, f32);
    #pragma unroll
    for (int j = 0; j < 4; ++j) {
        const int li = l - 3 + j;
        if (li >= 0)
            acc += bf2f(u[(size_t)(tok - 3 + j) * D_INNER + d]) * ldx(cw, d * 4 + j, f32);
    }
    us[idx] = f2bf(acc / (1.f + __expf(-acc)));    // silu
}

// -------- delta = softplus(delta_lin + b_dt), in place on (T, D_INNER) --------
__global__ __launch_bounds__(256) void softplus_kernel(u16* __restrict__ delta,
    const void* __restrict__ b_dt, const int* __restrict__ flagp)
{
    const bool f32 = (*flagp != 0);
    const int idx = blockIdx.x * 256 + threadIdx.x;
    const float xv = bf2f(delta[idx]) + ldx(b_dt, idx % D_INNER, f32);
    delta[idx] = f2bf((xv > 20.f) ? xv : log1pf(__expf(xv)));
}

// ------------- selective scan + C-contract + D skip + SiLU(v) gate -------------
__global__ __launch_bounds__(256) void scan_kernel(
    const u16* __restrict__ delta, const u16* __restrict__ us,
    const u16* __restrict__ xdbl, const u16* __restrict__ v,
    const void* __restrict__ log_A, const void* __restrict__ D_param,
    u16* __restrict__ y, const int* __restrict__ flagp)
{
    const bool f32 = (*flagp != 0);
    const int tid = threadIdx.x;
    const int n   = tid & 15;
    const int b   = blockIdx.x / (D_INNER / 16);
    const int dg  = blockIdx.x % (D_INNER / 16);
    const int d   = dg * 16 + (tid >> 4);
    const float A_dn = -__expf(ldx(log_A, d * D_STATE + n, f32));
    const float Dd   = ldx(D_param, d, f32);
    float h = 0.f;
    size_t tok = (size_t)b * LL;
    for (int l = 0; l < LL; ++l, ++tok) {
        const float dl = bf2f(delta[tok * D_INNER + d]);
        const float ul = bf2f(us[tok * D_INNER + d]);
        const float Bn = bf2f(xdbl[tok * 128 + DT_RANK + n]);
        const float Cn = bf2f(xdbl[tok * 128 + DT_RANK + D_STATE + n]);
        h = __expf(dl * A_dn) * h + (dl * ul) * Bn;   // h = A_bar*h + delta*B*u
        float p = h * Cn;
        p += __shfl_xor(p, 8, 16);
        p += __shfl_xor(p, 4, 16);
        p += __shfl_xor(p, 2, 16);
        p += __shfl_xor(p, 1, 16);
        if (n == 0) {
            const float vv = bf2f(v[tok * D_INNER + d]);
            y[tok * D_INNER + d] = f2bf((p + ul * Dd) * (vv / (1.f + __expf(-vv))));
        }
    }
}

extern "C" void kernel_launch(void* const* d_in, const int* in_sizes, int n_in,
                              void* d_out, int out_size, void* d_ws, size_t ws_size,
                              hipStream_t stream)
{
    const void* x      = d_in[0];
    const void* ln_g   = d_in[1];
    const void* ln_b   = d_in[2];
    const void* W_in   = d_in[3];
    const void* conv_w = d_in[4];
    const void* conv_b = d_in[5];
    const void* W_xp   = d_in[6];
    const void* W_dt   = d_in[7];
    const void* b_dt   = d_in[8];
    const void* log_A  = d_in[9];
    const void* D_par  = d_in[10];
    const void* W_out  = d_in[11];

    // workspace: [flag:512B][bf16 buffers: 57.7 MB]
    int* flag  = (int*)d_ws;
    u16* ws    = (u16*)((char*)d_ws + 512);
    u16* xn    = ws;                                  // T*768
    u16* u     = xn    + (size_t)TT * D_MODEL;        // T*1536
    u16* v     = u     + (size_t)TT * D_INNER;        // T*1536
    u16* us    = v     + (size_t)TT * D_INNER;        // T*1536
    u16* xdbl  = us    + (size_t)TT * D_INNER;        // T*128
    u16* delta = xdbl  + (size_t)TT * 128;            // T*1536
    u16* y     = u;                                   // overlay: u dead after conv

    // 0. dtype detect (fp32 vs bf16)
    detect_kernel<<<1, 256, 0, stream>>>(x, flag);
    // 1. LayerNorm
    ln_kernel<<<TT, 256, 0, stream>>>(x, ln_g, ln_b, xn, flag);
    // 2a. u = xn @ W_in[:, :1536]
    gemm_kernel<false><<<dim3(D_INNER / 64, TT / 64), 256, 0, stream>>>(
        xn, W_in, u, nullptr, nullptr, flag, TT, D_INNER, D_MODEL, D_MODEL, 2 * D_INNER, 0, D_INNER);
    // 2b. v = xn @ W_in[:, 1536:]
    gemm_kernel<false><<<dim3(D_INNER / 64, TT / 64), 256, 0, stream>>>(
        xn, W_in, v, nullptr, nullptr, flag, TT, D_INNER, D_MODEL, D_MODEL, 2 * D_INNER, D_INNER, D_INNER);
    // 3. us = silu(causal_conv(u))
    conv_silu_kernel<<<(TT * D_INNER) / 256, 256, 0, stream>>>(u, conv_w, conv_b, us, flag);
    // 4. x_dbl = us @ W_xproj   (4096x1536 * 1536x128)
    gemm_kernel<false><<<dim3(128 / 64, TT / 64), 256, 0, stream>>>(
        us, W_xp, xdbl, nullptr, nullptr, flag, TT, 128, D_INNER, D_INNER, 128, 0, 128);
    // 5. delta_lin = x_dbl[:, :96] @ W_dt   (4096x96 * 96x1536), lda=128
    gemm_kernel<false><<<dim3(D_INNER / 64, TT / 64), 256, 0, stream>>>(
        xdbl, W_dt, delta, nullptr, nullptr, flag, TT, D_INNER, DT_RANK, 128, D_INNER, 0, D_INNER);
    // 6. delta = softplus(delta_lin + b_dt)
    softplus_kernel<<<(TT * D_INNER) / 256, 256, 0, stream>>>(delta, b_dt, flag);
    // 7. selective scan -> y (gated by silu(v), with u*D skip); y overlays u
    scan_kernel<<<BB * (D_INNER / 16), 256, 0, stream>>>(delta, us, xdbl, v, log_A, D_par, y, flag);
    // 8. out = y @ W_out + x   (4096x1536 * 1536x768), flex-dtype out
    gemm_kernel<true><<<dim3(D_MODEL / 64, TT / 64), 256, 0, stream>>>(
        y, W_out, nullptr, d_out, x, flag, TT, D_MODEL, D_INNER, D_INNER, D_MODEL, 0, D_MODEL);
}

// Round 4
// 622.566 us; speedup vs baseline: 3.4542x; 3.4542x over previous
//
#include <hip/hip_runtime.h>

#define D_MODEL 768
#define D_INNER 1536
#define D_STATE 16
#define DT_RANK 96
#define BB 2
#define LL 2048
#define TT (BB*LL)          // 4096 tokens
#define NC 16               // chunks per sequence
#define CL 128              // chunk length (NC*CL == LL)

typedef unsigned short u16;
typedef short bf16x8 __attribute__((ext_vector_type(8)));
typedef float f32x4  __attribute__((ext_vector_type(4)));

__device__ __forceinline__ float bf2f(u16 u) {
    union { unsigned int i; float f; } c; c.i = ((unsigned int)u) << 16; return c.f;
}
__device__ __forceinline__ u16 f2bf(float f) {
    union { float f; unsigned int i; } c; c.f = f;
    unsigned int x = c.i;
    return (u16)((x + 0x7fffu + ((x >> 16) & 1u)) >> 16);   // RNE
}
// dtype-flex input loads (harness may hand us fp32 per reference, or bf16)
__device__ __forceinline__ float ldx(const void* p, size_t i, bool f32) {
    return f32 ? ((const float*)p)[i] : bf2f(((const u16*)p)[i]);
}
__device__ __forceinline__ float4 ldx4(const void* p, size_t i, bool f32) {
    if (f32) return *(const float4*)((const float*)p + i);
    ushort4 q = *(const ushort4*)((const u16*)p + i);
    float4 r; r.x = bf2f(q.x); r.y = bf2f(q.y); r.z = bf2f(q.z); r.w = bf2f(q.w);
    return r;
}

// ---- dtype detect: if buffer is fp32, even-index u16s are mantissa-low garbage ----
__global__ void detect_kernel(const void* x, int* flag)
{
    __shared__ int bad;
    if (threadIdx.x == 0) bad = 0;
    __syncthreads();
    const u16* p = (const u16*)x;
    int local = 0;
    for (int i = threadIdx.x; i < 2048; i += 256) {
        const float v = bf2f(p[2 * i]);
        if (!(fabsf(v) < 1e4f)) local = 1;   // catches huge exponents AND NaN
    }
    if (local) atomicOr(&bad, 1);
    __syncthreads();
    if (threadIdx.x == 0) *flag = bad;       // 1 => inputs are fp32
}

// ---------------- LayerNorm: x (T,768) -> xn (T,768) bf16 ----------------
__global__ __launch_bounds__(256) void ln_kernel(const void* __restrict__ x,
    const void* __restrict__ g, const void* __restrict__ b, u16* __restrict__ xn,
    const int* __restrict__ flagp)
{
    const bool f32 = (*flagp != 0);
    const int tok = blockIdx.x;
    const int tid = threadIdx.x;
    const size_t base = (size_t)tok * D_MODEL;
    float v[3];
    v[0] = ldx(x, base + tid, f32);
    v[1] = ldx(x, base + tid + 256, f32);
    v[2] = ldx(x, base + tid + 512, f32);
    float s = v[0] + v[1] + v[2];
    float q = v[0]*v[0] + v[1]*v[1] + v[2]*v[2];
    #pragma unroll
    for (int o = 32; o > 0; o >>= 1) {
        s += __shfl_down(s, o, 64);
        q += __shfl_down(q, o, 64);
    }
    __shared__ float ss[4], qq[4];
    if ((tid & 63) == 0) { ss[tid >> 6] = s; qq[tid >> 6] = q; }
    __syncthreads();
    const float S = ss[0] + ss[1] + ss[2] + ss[3];
    const float Q = qq[0] + qq[1] + qq[2] + qq[3];
    const float mu  = S * (1.f / D_MODEL);
    const float var = Q * (1.f / D_MODEL) - mu * mu;
    const float rs  = rsqrtf(var + 1e-5f);
    u16* outr = xn + base;
    #pragma unroll
    for (int i = 0; i < 3; ++i) {
        const int c = tid + i * 256;
        outr[c] = f2bf((v[i] - mu) * rs * ldx(g, c, f32) + ldx(b, c, f32));
    }
}

// ---------------- MFMA GEMM: 64x64 tile, BK=32, 4 waves/block ----------------
// C(M,N) = A(M,K)[bf16 ws] * B(K,N)[flex input].  fp32 acc.
// EPI 0: plain bf16 store. EPI 1: softplus(acc + bias[col]) bf16 store.
// EPI 2: acc + res[idx], store to flex-dtype Cout.
#define SA 40   // LDS row strides (bf16 units), padded
#define SB 40
template<int EPI>
__global__ __launch_bounds__(256) void mfma_gemm(
    const u16* __restrict__ A, const void* __restrict__ Bw,
    u16* __restrict__ C, void* __restrict__ Cout, const void* __restrict__ aux,
    const int* __restrict__ flagp,
    int K, int lda, int ldb, int ldc)
{
    const bool f32 = (*flagp != 0);
    __shared__ u16 As[64 * SA];
    __shared__ u16 Bs[64 * SB];
    const int tid  = threadIdx.x;
    const int wave = tid >> 6, lane = tid & 63;
    const int lrow = lane & 15, quad = lane >> 4;
    const int row0 = blockIdx.y * 64, col0 = blockIdx.x * 64;
    const int ar = tid >> 3,  ac = (tid & 7) * 4;   // A staging: (row, k4)
    const int bk = tid >> 4,  bn = (tid & 15) * 4;  // B staging: (k, n4)
    f32x4 acc[4] = {{0.f,0.f,0.f,0.f},{0.f,0.f,0.f,0.f},{0.f,0.f,0.f,0.f},{0.f,0.f,0.f,0.f}};
    for (int kt = 0; kt < K; kt += 32) {
        #pragma unroll
        for (int p = 0; p < 2; ++p) {
            const int r = ar + p * 32;
            *(ushort4*)(&As[r * SA + ac]) =
                *(const ushort4*)(A + (size_t)(row0 + r) * lda + kt + ac);
        }
        #pragma unroll
        for (int p = 0; p < 2; ++p) {
            const int k = bk + p * 16;
            const float4 b4 = ldx4(Bw, (size_t)(kt + k) * ldb + col0 + bn, f32);
            Bs[(bn + 0) * SB + k] = f2bf(b4.x);
            Bs[(bn + 1) * SB + k] = f2bf(b4.y);
            Bs[(bn + 2) * SB + k] = f2bf(b4.z);
            Bs[(bn + 3) * SB + k] = f2bf(b4.w);
        }
        __syncthreads();
        const bf16x8 af = *(const bf16x8*)(&As[(wave * 16 + lrow) * SA + quad * 8]);
        #pragma unroll
        for (int t = 0; t < 4; ++t) {
            const bf16x8 bf_ = *(const bf16x8*)(&Bs[(t * 16 + lrow) * SB + quad * 8]);
            acc[t] = __builtin_amdgcn_mfma_f32_16x16x32_bf16(af, bf_, acc[t], 0, 0, 0);
        }
        __syncthreads();
    }
    #pragma unroll
    for (int t = 0; t < 4; ++t) {
        #pragma unroll
        for (int r = 0; r < 4; ++r) {
            const int row = row0 + wave * 16 + quad * 4 + r;   // C/D: row=quad*4+reg
            const int col = col0 + t * 16 + lrow;              //      col=lane&15
            const size_t idx = (size_t)row * ldc + col;
            float vv = acc[t][r];
            if (EPI == 1) {
                vv += ldx(aux, col, f32);
                vv = (vv > 20.f) ? vv : log1pf(__expf(vv));
                C[idx] = f2bf(vv);
            } else if (EPI == 2) {
                vv += ldx(aux, idx, f32);
                if (f32) ((float*)Cout)[idx] = vv;
                else     ((u16*)Cout)[idx]   = f2bf(vv);
            } else {
                C[idx] = f2bf(vv);
            }
        }
    }
}

// ---- causal depthwise conv (width 4, left-pad 3) + SiLU: uv[:, :1536] -> us ----
__global__ __launch_bounds__(256) void conv_silu_kernel(
    const u16* __restrict__ uv, const void* __restrict__ cw, const void* __restrict__ cb,
    u16* __restrict__ us, const int* __restrict__ flagp)
{
    const bool f32 = (*flagp != 0);
    const int idx = blockIdx.x * 256 + threadIdx.x;   // over T*D_INNER
    const int d   = idx % D_INNER;
    const int tok = idx / D_INNER;
    const int l   = tok & (LL - 1);
    float acc = ldx(cb, d, f32);
    #pragma unroll
    for (int j = 0; j < 4; ++j) {
        const int li = l - 3 + j;
        if (li >= 0)
            acc += bf2f(uv[(size_t)(tok - 3 + j) * (2*D_INNER) + d]) * ldx(cw, d * 4 + j, f32);
    }
    us[idx] = f2bf(acc / (1.f + __expf(-acc)));    // silu
}

// -------- scan pass 1: per-chunk local scan -> carries (Pi a, h_local_end) --------
// block: (dg=bIdx.x in [0,96), chunk=bIdx.y, b=bIdx.z); thread: d_local*16 + n
__global__ __launch_bounds__(256) void scan1_kernel(
    const u16* __restrict__ delta, const u16* __restrict__ us,
    const u16* __restrict__ xdbl, const void* __restrict__ log_A,
    float* __restrict__ carryA, float* __restrict__ carryH,
    const int* __restrict__ flagp)
{
    const bool f32 = (*flagp != 0);
    const int tid = threadIdx.x;
    const int n = tid & 15, d = blockIdx.x * 16 + (tid >> 4);
    const int c = blockIdx.y, b = blockIdx.z;
    const float A_dn = -__expf(ldx(log_A, d * D_STATE + n, f32));
    float h = 0.f, P = 1.f;
    size_t tok = (size_t)b * LL + c * CL;
    for (int t = 0; t < CL; ++t, ++tok) {
        const float dl = bf2f(delta[tok * D_INNER + d]);
        const float ul = bf2f(us[tok * D_INNER + d]);
        const float Bn = bf2f(xdbl[tok * 128 + DT_RANK + n]);
        const float a  = __expf(dl * A_dn);
        h = a * h + (dl * ul) * Bn;
        P *= a;
    }
    const size_t ci = (((size_t)b * NC + c) * D_INNER + d) * D_STATE + n;
    carryA[ci] = P;
    carryH[ci] = h;
}

// -------- scan pass 2: exclusive scan over chunk carries, in place on carryH --------
__global__ __launch_bounds__(256) void scan2_kernel(
    const float* __restrict__ carryA, float* __restrict__ carryH)
{
    const int gid = blockIdx.x * 256 + threadIdx.x;        // over BB * D_INNER * D_STATE
    const int b   = gid / (D_INNER * D_STATE);
    const int dn  = gid % (D_INNER * D_STATE);
    float hrun = 0.f;
    #pragma unroll
    for (int c = 0; c < NC; ++c) {
        const size_t ci = ((size_t)(b * NC + c) * D_INNER * D_STATE) + dn;
        const float a = carryA[ci], hh = carryH[ci];
        carryH[ci] = hrun;                                  // exclusive prefix
        hrun = a * hrun + hh;
    }
}

// ------ scan pass 3: re-run chunk seeded with carry; emit y = gated output ------
// y written into uv[:, :1536] (u-columns are dead after conv)
__global__ __launch_bounds__(256) void scan3_kernel(
    const u16* __restrict__ delta, const u16* __restrict__ us,
    const u16* __restrict__ xdbl, u16* __restrict__ uv,
    const void* __restrict__ log_A, const void* __restrict__ D_param,
    const float* __restrict__ carryH, const int* __restrict__ flagp)
{
    const bool f32 = (*flagp != 0);
    const int tid = threadIdx.x;
    const int n = tid & 15, d = blockIdx.x * 16 + (tid >> 4);
    const int c = blockIdx.y, b = blockIdx.z;
    const float A_dn = -__expf(ldx(log_A, d * D_STATE + n, f32));
    const float Dd   = ldx(D_param, d, f32);
    float h = carryH[(((size_t)b * NC + c) * D_INNER + d) * D_STATE + n];
    size_t tok = (size_t)b * LL + c * CL;
    for (int t = 0; t < CL; ++t, ++tok) {
        const float dl = bf2f(delta[tok * D_INNER + d]);
        const float ul = bf2f(us[tok * D_INNER + d]);
        const float Bn = bf2f(xdbl[tok * 128 + DT_RANK + n]);
        const float Cn = bf2f(xdbl[tok * 128 + DT_RANK + D_STATE + n]);
        h = __expf(dl * A_dn) * h + (dl * ul) * Bn;
        float p = h * Cn;
        p += __shfl_xor(p, 8, 16);
        p += __shfl_xor(p, 4, 16);
        p += __shfl_xor(p, 2, 16);
        p += __shfl_xor(p, 1, 16);
        if (n == 0) {
            const float vv = bf2f(uv[tok * (2*D_INNER) + D_INNER + d]);
            uv[tok * (2*D_INNER) + d] = f2bf((p + ul * Dd) * (vv / (1.f + __expf(-vv))));
        }
    }
}

extern "C" void kernel_launch(void* const* d_in, const int* in_sizes, int n_in,
                              void* d_out, int out_size, void* d_ws, size_t ws_size,
                              hipStream_t stream)
{
    const void* x      = d_in[0];
    const void* ln_g   = d_in[1];
    const void* ln_b   = d_in[2];
    const void* W_in   = d_in[3];
    const void* conv_w = d_in[4];
    const void* conv_b = d_in[5];
    const void* W_xp   = d_in[6];
    const void* W_dt   = d_in[7];
    const void* b_dt   = d_in[8];
    const void* log_A  = d_in[9];
    const void* D_par  = d_in[10];
    const void* W_out  = d_in[11];

    // workspace: [flag 512B][xn T*768 bf16 — later overlaid by fp32 carries]
    //            [uv T*3072][us T*1536][xdbl T*128][delta T*1536]   total 57.7 MB
    int* flag  = (int*)d_ws;
    u16* ws    = (u16*)((char*)d_ws + 512);
    u16* xn    = ws;
    u16* uv    = xn + (size_t)TT * D_MODEL;
    u16* us    = uv + (size_t)TT * 2 * D_INNER;
    u16* xdbl  = us + (size_t)TT * D_INNER;
    u16* delta = xdbl + (size_t)TT * 128;
    // carries overlay xn (dead after GEMM-uv): 2 x 3.15 MB fp32 == 6.29 MB == |xn|
    float* carryA = (float*)xn;
    float* carryH = carryA + (size_t)BB * NC * D_INNER * D_STATE;

    detect_kernel<<<1, 256, 0, stream>>>(x, flag);
    ln_kernel<<<TT, 256, 0, stream>>>(x, ln_g, ln_b, xn, flag);
    // uv = xn @ W_in  (4096x3072, K=768)
    mfma_gemm<0><<<dim3(2 * D_INNER / 64, TT / 64), 256, 0, stream>>>(
        xn, W_in, uv, nullptr, nullptr, flag, D_MODEL, D_MODEL, 2 * D_INNER, 2 * D_INNER);
    // us = silu(causal_conv(uv[:, :1536]))
    conv_silu_kernel<<<(TT * D_INNER) / 256, 256, 0, stream>>>(uv, conv_w, conv_b, us, flag);
    // xdbl = us @ W_xproj  (4096x128, K=1536)
    mfma_gemm<0><<<dim3(128 / 64, TT / 64), 256, 0, stream>>>(
        us, W_xp, xdbl, nullptr, nullptr, flag, D_INNER, D_INNER, 128, 128);
    // delta = softplus(xdbl[:, :96] @ W_dt + b_dt)  (4096x1536, K=96, lda=128)
    mfma_gemm<1><<<dim3(D_INNER / 64, TT / 64), 256, 0, stream>>>(
        xdbl, W_dt, delta, nullptr, b_dt, flag, DT_RANK, 128, D_INNER, D_INNER);
    // chunked selective scan
    scan1_kernel<<<dim3(D_INNER / 16, NC, BB), 256, 0, stream>>>(
        delta, us, xdbl, log_A, carryA, carryH, flag);
    scan2_kernel<<<(BB * D_INNER * D_STATE) / 256, 256, 0, stream>>>(carryA, carryH);
    scan3_kernel<<<dim3(D_INNER / 16, NC, BB), 256, 0, stream>>>(
        delta, us, xdbl, uv, log_A, D_par, carryH, flag);
    // out = y @ W_out + x  (4096x768, K=1536, A=uv with lda=3072)
    mfma_gemm<2><<<dim3(D_MODEL / 64, TT / 64), 256, 0, stream>>>(
        uv, W_out, nullptr, d_out, x, flag, D_INNER, 2 * D_INNER, D_MODEL, D_MODEL);
}

// Round 5
// 549.573 us; speedup vs baseline: 3.9129x; 1.1328x over previous
//
#include <hip/hip_runtime.h>

#define D_MODEL 768
#define D_INNER 1536
#define D_STATE 16
#define DT_RANK 96
#define BB 2
#define LL 2048
#define TT (BB*LL)          // 4096 tokens
#define NC 16               // chunks per sequence
#define CL 128              // chunk length (NC*CL == LL)
#define DPB 128             // d's per scan block (256 thr = 128 d x 2 halves)

typedef unsigned short u16;
typedef short bf16x8 __attribute__((ext_vector_type(8)));
typedef float f32x4  __attribute__((ext_vector_type(4)));

__device__ __forceinline__ float bf2f(u16 u) {
    union { unsigned int i; float f; } c; c.i = ((unsigned int)u) << 16; return c.f;
}
__device__ __forceinline__ u16 f2bf(float f) {
    union { float f; unsigned int i; } c; c.f = f;
    unsigned int x = c.i;
    return (u16)((x + 0x7fffu + ((x >> 16) & 1u)) >> 16);   // RNE
}
// unpack packed bf16 pair (from a uint) to fp32
__device__ __forceinline__ float bfu_lo(unsigned int u) {
    union { unsigned int i; float f; } c; c.i = u << 16; return c.f;
}
__device__ __forceinline__ float bfu_hi(unsigned int u) {
    union { unsigned int i; float f; } c; c.i = u & 0xFFFF0000u; return c.f;
}
// dtype-flex input loads (harness may hand us fp32 per reference, or bf16)
__device__ __forceinline__ float ldx(const void* p, size_t i, bool f32) {
    return f32 ? ((const float*)p)[i] : bf2f(((const u16*)p)[i]);
}
__device__ __forceinline__ float4 ldx4(const void* p, size_t i, bool f32) {
    if (f32) return *(const float4*)((const float*)p + i);
    ushort4 q = *(const ushort4*)((const u16*)p + i);
    float4 r; r.x = bf2f(q.x); r.y = bf2f(q.y); r.z = bf2f(q.z); r.w = bf2f(q.w);
    return r;
}

// ---- dtype detect: if buffer is fp32, even-index u16s are mantissa-low garbage ----
__global__ void detect_kernel(const void* x, int* flag)
{
    __shared__ int bad;
    if (threadIdx.x == 0) bad = 0;
    __syncthreads();
    const u16* p = (const u16*)x;
    int local = 0;
    for (int i = threadIdx.x; i < 2048; i += 256) {
        const float v = bf2f(p[2 * i]);
        if (!(fabsf(v) < 1e4f)) local = 1;   // catches huge exponents AND NaN
    }
    if (local) atomicOr(&bad, 1);
    __syncthreads();
    if (threadIdx.x == 0) *flag = bad;       // 1 => inputs are fp32
}

// ---------------- LayerNorm: x (T,768) -> xn (T,768) bf16 ----------------
__global__ __launch_bounds__(256) void ln_kernel(const void* __restrict__ x,
    const void* __restrict__ g, const void* __restrict__ b, u16* __restrict__ xn,
    const int* __restrict__ flagp)
{
    const bool f32 = (*flagp != 0);
    const int tok = blockIdx.x;
    const int tid = threadIdx.x;
    const size_t base = (size_t)tok * D_MODEL;
    float v[3];
    v[0] = ldx(x, base + tid, f32);
    v[1] = ldx(x, base + tid + 256, f32);
    v[2] = ldx(x, base + tid + 512, f32);
    float s = v[0] + v[1] + v[2];
    float q = v[0]*v[0] + v[1]*v[1] + v[2]*v[2];
    #pragma unroll
    for (int o = 32; o > 0; o >>= 1) {
        s += __shfl_down(s, o, 64);
        q += __shfl_down(q, o, 64);
    }
    __shared__ float ss[4], qq[4];
    if ((tid & 63) == 0) { ss[tid >> 6] = s; qq[tid >> 6] = q; }
    __syncthreads();
    const float S = ss[0] + ss[1] + ss[2] + ss[3];
    const float Q = qq[0] + qq[1] + qq[2] + qq[3];
    const float mu  = S * (1.f / D_MODEL);
    const float var = Q * (1.f / D_MODEL) - mu * mu;
    const float rs  = rsqrtf(var + 1e-5f);
    u16* outr = xn + base;
    #pragma unroll
    for (int i = 0; i < 3; ++i) {
        const int c = tid + i * 256;
        outr[c] = f2bf((v[i] - mu) * rs * ldx(g, c, f32) + ldx(b, c, f32));
    }
}

// ---------------- MFMA GEMM: 64x64 tile, BK=32, 4 waves/block ----------------
// C(M,N) = A(M,K)[bf16 ws] * B(K,N)[flex input].  fp32 acc.
// EPI 0: plain bf16 store. EPI 1: softplus(acc + bias[col]) bf16 store.
// EPI 2: acc + res[idx], store to flex-dtype Cout.
#define SA 40   // LDS row strides (bf16 units), padded
#define SB 40
template<int EPI>
__global__ __launch_bounds__(256) void mfma_gemm(
    const u16* __restrict__ A, const void* __restrict__ Bw,
    u16* __restrict__ C, void* __restrict__ Cout, const void* __restrict__ aux,
    const int* __restrict__ flagp,
    int K, int lda, int ldb, int ldc)
{
    const bool f32 = (*flagp != 0);
    __shared__ u16 As[64 * SA];
    __shared__ u16 Bs[64 * SB];
    const int tid  = threadIdx.x;
    const int wave = tid >> 6, lane = tid & 63;
    const int lrow = lane & 15, quad = lane >> 4;
    const int row0 = blockIdx.y * 64, col0 = blockIdx.x * 64;
    const int ar = tid >> 3,  ac = (tid & 7) * 4;   // A staging: (row, k4)
    const int bk = tid >> 4,  bn = (tid & 15) * 4;  // B staging: (k, n4)
    f32x4 acc[4] = {{0.f,0.f,0.f,0.f},{0.f,0.f,0.f,0.f},{0.f,0.f,0.f,0.f},{0.f,0.f,0.f,0.f}};
    for (int kt = 0; kt < K; kt += 32) {
        #pragma unroll
        for (int p = 0; p < 2; ++p) {
            const int r = ar + p * 32;
            *(ushort4*)(&As[r * SA + ac]) =
                *(const ushort4*)(A + (size_t)(row0 + r) * lda + kt + ac);
        }
        #pragma unroll
        for (int p = 0; p < 2; ++p) {
            const int k = bk + p * 16;
            const float4 b4 = ldx4(Bw, (size_t)(kt + k) * ldb + col0 + bn, f32);
            Bs[(bn + 0) * SB + k] = f2bf(b4.x);
            Bs[(bn + 1) * SB + k] = f2bf(b4.y);
            Bs[(bn + 2) * SB + k] = f2bf(b4.z);
            Bs[(bn + 3) * SB + k] = f2bf(b4.w);
        }
        __syncthreads();
        const bf16x8 af = *(const bf16x8*)(&As[(wave * 16 + lrow) * SA + quad * 8]);
        #pragma unroll
        for (int t = 0; t < 4; ++t) {
            const bf16x8 bf_ = *(const bf16x8*)(&Bs[(t * 16 + lrow) * SB + quad * 8]);
            acc[t] = __builtin_amdgcn_mfma_f32_16x16x32_bf16(af, bf_, acc[t], 0, 0, 0);
        }
        __syncthreads();
    }
    #pragma unroll
    for (int t = 0; t < 4; ++t) {
        #pragma unroll
        for (int r = 0; r < 4; ++r) {
            const int row = row0 + wave * 16 + quad * 4 + r;   // C/D: row=quad*4+reg
            const int col = col0 + t * 16 + lrow;              //      col=lane&15
            const size_t idx = (size_t)row * ldc + col;
            float vv = acc[t][r];
            if (EPI == 1) {
                vv += ldx(aux, col, f32);
                vv = (vv > 20.f) ? vv : log1pf(__expf(vv));
                C[idx] = f2bf(vv);
            } else if (EPI == 2) {
                vv += ldx(aux, idx, f32);
                if (f32) ((float*)Cout)[idx] = vv;
                else     ((u16*)Cout)[idx]   = f2bf(vv);
            } else {
                C[idx] = f2bf(vv);
            }
        }
    }
}

// ---- causal depthwise conv (width 4, left-pad 3) + SiLU: uv[:, :1536] -> us ----
__global__ __launch_bounds__(256) void conv_silu_kernel(
    const u16* __restrict__ uv, const void* __restrict__ cw, const void* __restrict__ cb,
    u16* __restrict__ us, const int* __restrict__ flagp)
{
    const bool f32 = (*flagp != 0);
    const int idx = blockIdx.x * 256 + threadIdx.x;   // over T*D_INNER
    const int d   = idx % D_INNER;
    const int tok = idx / D_INNER;
    const int l   = tok & (LL - 1);
    float acc = ldx(cb, d, f32);
    #pragma unroll
    for (int j = 0; j < 4; ++j) {
        const int li = l - 3 + j;
        if (li >= 0)
            acc += bf2f(uv[(size_t)(tok - 3 + j) * (2*D_INNER) + d]) * ldx(cw, d * 4 + j, f32);
    }
    us[idx] = f2bf(acc / (1.f + __expf(-acc)));    // silu
}

// ----- scan pass 1: per-chunk local scan -> carries (prod a, h_local_end) -----
// thread = (d = bx*DPB + tid/2, half = tid&1 -> n in [half*8, half*8+8))
// h[8] in VGPRs; B row is a wave-uniform broadcast load; no cross-lane ops.
// chunk product of a's computed as exp(A_n * sum_t delta_t)  (1 add/t).
__global__ __launch_bounds__(256) void scan1_kernel(
    const u16* __restrict__ delta, const u16* __restrict__ us,
    const u16* __restrict__ xdbl, const void* __restrict__ log_A,
    float* __restrict__ carryA, float* __restrict__ carryH,
    const int* __restrict__ flagp)
{
    const bool f32 = (*flagp != 0);
    const int tid  = threadIdx.x;
    const int half = tid & 1;
    const int d    = blockIdx.x * DPB + (tid >> 1);
    const int c    = blockIdx.y, b = blockIdx.z;
    float A_[8], h[8];
    #pragma unroll
    for (int j = 0; j < 8; ++j) {
        A_[j] = -__expf(ldx(log_A, d * D_STATE + half * 8 + j, f32));
        h[j] = 0.f;
    }
    float sdl = 0.f;
    size_t tok = (size_t)b * LL + c * CL;
    for (int t = 0; t < CL; ++t, ++tok) {
        const float dl = bf2f(delta[tok * D_INNER + d]);
        const float ul = bf2f(us[tok * D_INNER + d]);
        const uint4 Bu = *(const uint4*)(xdbl + tok * 128 + DT_RANK + half * 8);
        const float dlul = dl * ul;
        sdl += dl;
        const unsigned int bw[4] = {Bu.x, Bu.y, Bu.z, Bu.w};
        #pragma unroll
        for (int j = 0; j < 8; ++j) {
            const float Bn = (j & 1) ? bfu_hi(bw[j >> 1]) : bfu_lo(bw[j >> 1]);
            const float a  = __expf(dl * A_[j]);
            h[j] = a * h[j] + dlul * Bn;
        }
    }
    const size_t ci = (((size_t)b * NC + c) * D_INNER + d) * D_STATE + half * 8;
    #pragma unroll
    for (int j = 0; j < 8; ++j) {
        carryA[ci + j] = __expf(A_[j] * sdl);
        carryH[ci + j] = h[j];
    }
}

// -------- scan pass 2: exclusive scan over chunk carries, in place on carryH --------
__global__ __launch_bounds__(256) void scan2_kernel(
    const float* __restrict__ carryA, float* __restrict__ carryH)
{
    const int gid = blockIdx.x * 256 + threadIdx.x;        // over BB * D_INNER * D_STATE
    const int b   = gid / (D_INNER * D_STATE);
    const int dn  = gid % (D_INNER * D_STATE);
    float hrun = 0.f;
    #pragma unroll
    for (int c = 0; c < NC; ++c) {
        const size_t ci = ((size_t)(b * NC + c) * D_INNER * D_STATE) + dn;
        const float a = carryA[ci], hh = carryH[ci];
        carryH[ci] = hrun;                                  // exclusive prefix
        hrun = a * hrun + hh;
    }
}

// ------ scan pass 3: re-run chunk seeded with carry; emit y = gated output ------
// same layout as pass 1; per-t cross-lane cost = one shfl_xor(p,1).
// y written into uv[:, :1536] (u-columns dead after conv).
__global__ __launch_bounds__(256) void scan3_kernel(
    const u16* __restrict__ delta, const u16* __restrict__ us,
    const u16* __restrict__ xdbl, u16* __restrict__ uv,
    const void* __restrict__ log_A, const void* __restrict__ D_param,
    const float* __restrict__ carryH, const int* __restrict__ flagp)
{
    const bool f32 = (*flagp != 0);
    const int tid  = threadIdx.x;
    const int half = tid & 1;
    const int d    = blockIdx.x * DPB + (tid >> 1);
    const int c    = blockIdx.y, b = blockIdx.z;
    const float Dd = ldx(D_param, d, f32);
    float A_[8], h[8];
    const size_t ci = (((size_t)b * NC + c) * D_INNER + d) * D_STATE + half * 8;
    #pragma unroll
    for (int j = 0; j < 8; ++j) {
        A_[j] = -__expf(ldx(log_A, d * D_STATE + half * 8 + j, f32));
        h[j] = carryH[ci + j];
    }
    size_t tok = (size_t)b * LL + c * CL;
    for (int t = 0; t < CL; ++t, ++tok) {
        const float dl = bf2f(delta[tok * D_INNER + d]);
        const float ul = bf2f(us[tok * D_INNER + d]);
        const uint4 Bu = *(const uint4*)(xdbl + tok * 128 + DT_RANK + half * 8);
        const uint4 Cu = *(const uint4*)(xdbl + tok * 128 + DT_RANK + D_STATE + half * 8);
        const float dlul = dl * ul;
        const unsigned int bw[4] = {Bu.x, Bu.y, Bu.z, Bu.w};
        const unsigned int cw_[4] = {Cu.x, Cu.y, Cu.z, Cu.w};
        float p = 0.f;
        #pragma unroll
        for (int j = 0; j < 8; ++j) {
            const float Bn = (j & 1) ? bfu_hi(bw[j >> 1]) : bfu_lo(bw[j >> 1]);
            const float Cn = (j & 1) ? bfu_hi(cw_[j >> 1]) : bfu_lo(cw_[j >> 1]);
            const float a  = __expf(dl * A_[j]);
            h[j] = a * h[j] + dlul * Bn;
            p += h[j] * Cn;
        }
        p += __shfl_xor(p, 1, 64);          // combine the two n-halves
        if (half == 0) {
            const float vv = bf2f(uv[tok * (2*D_INNER) + D_INNER + d]);
            uv[tok * (2*D_INNER) + d] = f2bf((p + ul * Dd) * (vv / (1.f + __expf(-vv))));
        }
    }
}

extern "C" void kernel_launch(void* const* d_in, const int* in_sizes, int n_in,
                              void* d_out, int out_size, void* d_ws, size_t ws_size,
                              hipStream_t stream)
{
    const void* x      = d_in[0];
    const void* ln_g   = d_in[1];
    const void* ln_b   = d_in[2];
    const void* W_in   = d_in[3];
    const void* conv_w = d_in[4];
    const void* conv_b = d_in[5];
    const void* W_xp   = d_in[6];
    const void* W_dt   = d_in[7];
    const void* b_dt   = d_in[8];
    const void* log_A  = d_in[9];
    const void* D_par  = d_in[10];
    const void* W_out  = d_in[11];

    // workspace: [flag 512B][xn T*768 bf16 — later overlaid by fp32 carries]
    //            [uv T*3072][us T*1536][xdbl T*128][delta T*1536]   total 57.7 MB
    int* flag  = (int*)d_ws;
    u16* ws    = (u16*)((char*)d_ws + 512);
    u16* xn    = ws;
    u16* uv    = xn + (size_t)TT * D_MODEL;
    u16* us    = uv + (size_t)TT * 2 * D_INNER;
    u16* xdbl  = us + (size_t)TT * D_INNER;
    u16* delta = xdbl + (size_t)TT * 128;
    // carries overlay xn (dead after GEMM-uv): 2 x 3.15 MB fp32 == 6.29 MB == |xn|
    float* carryA = (float*)xn;
    float* carryH = carryA + (size_t)BB * NC * D_INNER * D_STATE;

    detect_kernel<<<1, 256, 0, stream>>>(x, flag);
    ln_kernel<<<TT, 256, 0, stream>>>(x, ln_g, ln_b, xn, flag);
    // uv = xn @ W_in  (4096x3072, K=768)
    mfma_gemm<0><<<dim3(2 * D_INNER / 64, TT / 64), 256, 0, stream>>>(
        xn, W_in, uv, nullptr, nullptr, flag, D_MODEL, D_MODEL, 2 * D_INNER, 2 * D_INNER);
    // us = silu(causal_conv(uv[:, :1536]))
    conv_silu_kernel<<<(TT * D_INNER) / 256, 256, 0, stream>>>(uv, conv_w, conv_b, us, flag);
    // xdbl = us @ W_xproj  (4096x128, K=1536)
    mfma_gemm<0><<<dim3(128 / 64, TT / 64), 256, 0, stream>>>(
        us, W_xp, xdbl, nullptr, nullptr, flag, D_INNER, D_INNER, 128, 128);
    // delta = softplus(xdbl[:, :96] @ W_dt + b_dt)  (4096x1536, K=96, lda=128)
    mfma_gemm<1><<<dim3(D_INNER / 64, TT / 64), 256, 0, stream>>>(
        xdbl, W_dt, delta, nullptr, b_dt, flag, DT_RANK, 128, D_INNER, D_INNER);
    // chunked selective scan (d-per-lane-pair layout)
    scan1_kernel<<<dim3(D_INNER / DPB, NC, BB), 256, 0, stream>>>(
        delta, us, xdbl, log_A, carryA, carryH, flag);
    scan2_kernel<<<(BB * D_INNER * D_STATE) / 256, 256, 0, stream>>>(carryA, carryH);
    scan3_kernel<<<dim3(D_INNER / DPB, NC, BB), 256, 0, stream>>>(
        delta, us, xdbl, uv, log_A, D_par, carryH, flag);
    // out = y @ W_out + x  (4096x768, K=1536, A=uv with lda=3072)
    mfma_gemm<2><<<dim3(D_MODEL / 64, TT / 64), 256, 0, stream>>>(
        uv, W_out, nullptr, d_out, x, flag, D_INNER, 2 * D_INNER, D_MODEL, D_MODEL);
}

// Round 7
// 453.975 us; speedup vs baseline: 4.7369x; 1.2106x over previous
//
#include <hip/hip_runtime.h>

#define D_MODEL 768
#define D_INNER 1536
#define D_STATE 16
#define DT_RANK 96
#define BB 2
#define LL 2048
#define TT (BB*LL)          // 4096 tokens
#define NC 32               // chunks per sequence
#define CL 64               // chunk length (NC*CL == LL)
#define DPB 128             // d's per scan block (256 thr = 128 d x 2 halves)

typedef unsigned short u16;
typedef short bf16x8 __attribute__((ext_vector_type(8)));
typedef unsigned short u16x8 __attribute__((ext_vector_type(8)));
typedef float f32x4  __attribute__((ext_vector_type(4)));

__device__ __forceinline__ float bf2f(u16 u) {
    union { unsigned int i; float f; } c; c.i = ((unsigned int)u) << 16; return c.f;
}
__device__ __forceinline__ u16 f2bf(float f) {
    union { float f; unsigned int i; } c; c.f = f;
    unsigned int x = c.i;
    return (u16)((x + 0x7fffu + ((x >> 16) & 1u)) >> 16);   // RNE
}
// unpack packed bf16 pair (from a uint) to fp32
__device__ __forceinline__ float bfu_lo(unsigned int u) {
    union { unsigned int i; float f; } c; c.i = u << 16; return c.f;
}
__device__ __forceinline__ float bfu_hi(unsigned int u) {
    union { unsigned int i; float f; } c; c.i = u & 0xFFFF0000u; return c.f;
}
// dtype-flex input loads (harness may hand us fp32 per reference, or bf16)
__device__ __forceinline__ float ldx(const void* p, size_t i, bool f32) {
    return f32 ? ((const float*)p)[i] : bf2f(((const u16*)p)[i]);
}
__device__ __forceinline__ float4 ldx4(const void* p, size_t i, bool f32) {
    if (f32) return *(const float4*)((const float*)p + i);
    ushort4 q = *(const ushort4*)((const u16*)p + i);
    float4 r; r.x = bf2f(q.x); r.y = bf2f(q.y); r.z = bf2f(q.z); r.w = bf2f(q.w);
    return r;
}

// ---- dtype detect: if buffer is fp32, even-index u16s are mantissa-low garbage ----
__global__ void detect_kernel(const void* x, int* flag)
{
    __shared__ int bad;
    if (threadIdx.x == 0) bad = 0;
    __syncthreads();
    const u16* p = (const u16*)x;
    int local = 0;
    for (int i = threadIdx.x; i < 2048; i += 256) {
        const float v = bf2f(p[2 * i]);
        if (!(fabsf(v) < 1e4f)) local = 1;   // catches huge exponents AND NaN
    }
    if (local) atomicOr(&bad, 1);
    __syncthreads();
    if (threadIdx.x == 0) *flag = bad;       // 1 => inputs are fp32
}

// ---------------- LayerNorm: x (T,768) -> xn (T,768) bf16 ----------------
__global__ __launch_bounds__(256) void ln_kernel(const void* __restrict__ x,
    const void* __restrict__ g, const void* __restrict__ b, u16* __restrict__ xn,
    const int* __restrict__ flagp)
{
    const bool f32 = (*flagp != 0);
    const int tok = blockIdx.x;
    const int tid = threadIdx.x;
    const size_t base = (size_t)tok * D_MODEL;
    float v[3];
    v[0] = ldx(x, base + tid, f32);
    v[1] = ldx(x, base + tid + 256, f32);
    v[2] = ldx(x, base + tid + 512, f32);
    float s = v[0] + v[1] + v[2];
    float q = v[0]*v[0] + v[1]*v[1] + v[2]*v[2];
    #pragma unroll
    for (int o = 32; o > 0; o >>= 1) {
        s += __shfl_down(s, o, 64);
        q += __shfl_down(q, o, 64);
    }
    __shared__ float ss[4], qq[4];
    if ((tid & 63) == 0) { ss[tid >> 6] = s; qq[tid >> 6] = q; }
    __syncthreads();
    const float S = ss[0] + ss[1] + ss[2] + ss[3];
    const float Q = qq[0] + qq[1] + qq[2] + qq[3];
    const float mu  = S * (1.f / D_MODEL);
    const float var = Q * (1.f / D_MODEL) - mu * mu;
    const float rs  = rsqrtf(var + 1e-5f);
    u16* outr = xn + base;
    #pragma unroll
    for (int i = 0; i < 3; ++i) {
        const int c = tid + i * 256;
        outr[c] = f2bf((v[i] - mu) * rs * ldx(g, c, f32) + ldx(b, c, f32));
    }
}

// ---------------- MFMA GEMM 64x64 tile, BK=32, 4 waves ----------------
// EPI 0: plain bf16 store. EPI 2: acc + res[idx], flex-dtype store.
#define SA 40
#define SB 40
template<int EPI>
__global__ __launch_bounds__(256) void mfma_gemm(
    const u16* __restrict__ A, const void* __restrict__ Bw,
    u16* __restrict__ C, void* __restrict__ Cout, const void* __restrict__ aux,
    const int* __restrict__ flagp,
    int K, int lda, int ldb, int ldc)
{
    const bool f32 = (*flagp != 0);
    __shared__ u16 As[64 * SA];
    __shared__ u16 Bs[64 * SB];
    const int tid  = threadIdx.x;
    const int wave = tid >> 6, lane = tid & 63;
    const int lrow = lane & 15, quad = lane >> 4;
    const int row0 = blockIdx.y * 64, col0 = blockIdx.x * 64;
    const int ar = tid >> 3,  ac = (tid & 7) * 4;   // A staging: (row, k4)
    const int bk = tid >> 4,  bn = (tid & 15) * 4;  // B staging: (k, n4)
    f32x4 acc[4] = {{0.f,0.f,0.f,0.f},{0.f,0.f,0.f,0.f},{0.f,0.f,0.f,0.f},{0.f,0.f,0.f,0.f}};
    for (int kt = 0; kt < K; kt += 32) {
        #pragma unroll
        for (int p = 0; p < 2; ++p) {
            const int r = ar + p * 32;
            *(ushort4*)(&As[r * SA + ac]) =
                *(const ushort4*)(A + (size_t)(row0 + r) * lda + kt + ac);
        }
        #pragma unroll
        for (int p = 0; p < 2; ++p) {
            const int k = bk + p * 16;
            const float4 b4 = ldx4(Bw, (size_t)(kt + k) * ldb + col0 + bn, f32);
            Bs[(bn + 0) * SB + k] = f2bf(b4.x);
            Bs[(bn + 1) * SB + k] = f2bf(b4.y);
            Bs[(bn + 2) * SB + k] = f2bf(b4.z);
            Bs[(bn + 3) * SB + k] = f2bf(b4.w);
        }
        __syncthreads();
        const bf16x8 af = *(const bf16x8*)(&As[(wave * 16 + lrow) * SA + quad * 8]);
        #pragma unroll
        for (int t = 0; t < 4; ++t) {
            const bf16x8 bf_ = *(const bf16x8*)(&Bs[(t * 16 + lrow) * SB + quad * 8]);
            acc[t] = __builtin_amdgcn_mfma_f32_16x16x32_bf16(af, bf_, acc[t], 0, 0, 0);
        }
        __syncthreads();
    }
    #pragma unroll
    for (int t = 0; t < 4; ++t) {
        #pragma unroll
        for (int r = 0; r < 4; ++r) {
            const int row = row0 + wave * 16 + quad * 4 + r;   // C/D: row=quad*4+reg
            const int col = col0 + t * 16 + lrow;              //      col=lane&15
            const size_t idx = (size_t)row * ldc + col;
            float vv = acc[t][r];
            if (EPI == 2) {
                vv += ldx(aux, idx, f32);
                if (f32) ((float*)Cout)[idx] = vv;
                else     ((u16*)Cout)[idx]   = f2bf(vv);
            } else {
                C[idx] = f2bf(vv);
            }
        }
    }
}

// ------------- MFMA GEMM 128x128 tile, BK=32, 4 waves (2x2), 4x4 tiles/wave -------------
// EPI 0: plain bf16 store. EPI 1: softplus(acc + bias[col]) bf16 store.
template<int EPI>
__global__ __launch_bounds__(256) void mfma_gemm128(
    const u16* __restrict__ A, const void* __restrict__ Bw,
    u16* __restrict__ C, const void* __restrict__ aux,
    const int* __restrict__ flagp,
    int K, int lda, int ldb, int ldc)
{
    const bool f32 = (*flagp != 0);
    __shared__ u16 As[128 * SA];
    __shared__ u16 Bs[128 * SB];
    const int tid  = threadIdx.x;
    const int wave = tid >> 6, lane = tid & 63;
    const int lrow = lane & 15, quad = lane >> 4;
    const int wy = wave >> 1, wx = wave & 1;
    const int row0 = blockIdx.y * 128, col0 = blockIdx.x * 128;
    const int ar = tid >> 1, ak = (tid & 1) * 16;   // A staging: 2 thr/row, 16 u16 each
    const int bkk = tid & 31, bng = (tid >> 5) * 4; // B staging: (k, n-group)
    f32x4 acc[4][4];
    #pragma unroll
    for (int i = 0; i < 4; ++i)
        #pragma unroll
        for (int j = 0; j < 4; ++j) acc[i][j] = (f32x4){0.f,0.f,0.f,0.f};
    for (int kt = 0; kt < K; kt += 32) {
        // FIX R6: each thread covers k = ak..ak+15 via TWO u16x8 loads (was one -> half tile stale)
        *(u16x8*)(&As[ar * SA + ak]) =
            *(const u16x8*)(A + (size_t)(row0 + ar) * lda + kt + ak);
        *(u16x8*)(&As[ar * SA + ak + 8]) =
            *(const u16x8*)(A + (size_t)(row0 + ar) * lda + kt + ak + 8);
        #pragma unroll
        for (int p = 0; p < 4; ++p) {
            const int n = bng + p * 32;
            const float4 b4 = ldx4(Bw, (size_t)(kt + bkk) * ldb + col0 + n, f32);
            Bs[(n + 0) * SB + bkk] = f2bf(b4.x);
            Bs[(n + 1) * SB + bkk] = f2bf(b4.y);
            Bs[(n + 2) * SB + bkk] = f2bf(b4.z);
            Bs[(n + 3) * SB + bkk] = f2bf(b4.w);
        }
        __syncthreads();
        bf16x8 af[4], bf_[4];
        #pragma unroll
        for (int i = 0; i < 4; ++i)
            af[i] = *(const bf16x8*)(&As[(wy * 64 + i * 16 + lrow) * SA + quad * 8]);
        #pragma unroll
        for (int j = 0; j < 4; ++j)
            bf_[j] = *(const bf16x8*)(&Bs[(wx * 64 + j * 16 + lrow) * SB + quad * 8]);
        #pragma unroll
        for (int i = 0; i < 4; ++i)
            #pragma unroll
            for (int j = 0; j < 4; ++j)
                acc[i][j] = __builtin_amdgcn_mfma_f32_16x16x32_bf16(af[i], bf_[j], acc[i][j], 0, 0, 0);
        __syncthreads();
    }
    #pragma unroll
    for (int i = 0; i < 4; ++i) {
        #pragma unroll
        for (int j = 0; j < 4; ++j) {
            #pragma unroll
            for (int r = 0; r < 4; ++r) {
                const int row = row0 + wy * 64 + i * 16 + quad * 4 + r;
                const int col = col0 + wx * 64 + j * 16 + lrow;
                const size_t idx = (size_t)row * ldc + col;
                float vv = acc[i][j][r];
                if (EPI == 1) {
                    vv += ldx(aux, col, f32);
                    vv = (vv > 20.f) ? vv : log1pf(__expf(vv));
                }
                C[idx] = f2bf(vv);
            }
        }
    }
}

// ---- causal depthwise conv (width 4, left-pad 3) + SiLU: uv[:, :1536] -> us ----
__global__ __launch_bounds__(256) void conv_silu_kernel(
    const u16* __restrict__ uv, const void* __restrict__ cw, const void* __restrict__ cb,
    u16* __restrict__ us, const int* __restrict__ flagp)
{
    const bool f32 = (*flagp != 0);
    const int idx = blockIdx.x * 256 + threadIdx.x;   // over T*D_INNER
    const int d   = idx % D_INNER;
    const int tok = idx / D_INNER;
    const int l   = tok & (LL - 1);
    float acc = ldx(cb, d, f32);
    #pragma unroll
    for (int j = 0; j < 4; ++j) {
        const int li = l - 3 + j;
        if (li >= 0)
            acc += bf2f(uv[(size_t)(tok - 3 + j) * (2*D_INNER) + d]) * ldx(cw, d * 4 + j, f32);
    }
    us[idx] = f2bf(acc / (1.f + __expf(-acc)));    // silu
}

// ----- scan pass 1: per-chunk local scan -> carries (prod a, h_local_end) -----
__global__ __launch_bounds__(256) void scan1_kernel(
    const u16* __restrict__ delta, const u16* __restrict__ us,
    const u16* __restrict__ xdbl, const void* __restrict__ log_A,
    float* __restrict__ carryA, float* __restrict__ carryH,
    const int* __restrict__ flagp)
{
    const bool f32 = (*flagp != 0);
    const int tid  = threadIdx.x;
    const int half = tid & 1;
    const int d    = blockIdx.x * DPB + (tid >> 1);
    const int c    = blockIdx.y, b = blockIdx.z;
    float A_[8], h[8];
    #pragma unroll
    for (int j = 0; j < 8; ++j) {
        A_[j] = -__expf(ldx(log_A, d * D_STATE + half * 8 + j, f32));
        h[j] = 0.f;
    }
    float sdl = 0.f;
    size_t tok = (size_t)b * LL + c * CL;
    for (int t = 0; t < CL; ++t, ++tok) {
        const float dl = bf2f(delta[tok * D_INNER + d]);
        const float ul = bf2f(us[tok * D_INNER + d]);
        const uint4 Bu = *(const uint4*)(xdbl + tok * 128 + DT_RANK + half * 8);
        const float dlul = dl * ul;
        sdl += dl;
        const unsigned int bw[4] = {Bu.x, Bu.y, Bu.z, Bu.w};
        #pragma unroll
        for (int j = 0; j < 8; ++j) {
            const float Bn = (j & 1) ? bfu_hi(bw[j >> 1]) : bfu_lo(bw[j >> 1]);
            const float a  = __expf(dl * A_[j]);
            h[j] = a * h[j] + dlul * Bn;
        }
    }
    const size_t ci = (((size_t)b * NC + c) * D_INNER + d) * D_STATE + half * 8;
    #pragma unroll
    for (int j = 0; j < 8; ++j) {
        carryA[ci + j] = __expf(A_[j] * sdl);
        carryH[ci + j] = h[j];
    }
}

// -------- scan pass 2: exclusive scan over chunk carries, in place on carryH --------
__global__ __launch_bounds__(256) void scan2_kernel(
    const float* __restrict__ carryA, float* __restrict__ carryH)
{
    const int gid = blockIdx.x * 256 + threadIdx.x;        // over BB * D_INNER * D_STATE
    const int b   = gid / (D_INNER * D_STATE);
    const int dn  = gid % (D_INNER * D_STATE);
    float hrun = 0.f;
    #pragma unroll
    for (int c = 0; c < NC; ++c) {
        const size_t ci = ((size_t)(b * NC + c) * D_INNER * D_STATE) + dn;
        const float a = carryA[ci], hh = carryH[ci];
        carryH[ci] = hrun;                                  // exclusive prefix
        hrun = a * hrun + hh;
    }
}

// ------ scan pass 3: re-run chunk seeded with carry; emit y = gated output ------
__global__ __launch_bounds__(256) void scan3_kernel(
    const u16* __restrict__ delta, const u16* __restrict__ us,
    const u16* __restrict__ xdbl, u16* __restrict__ uv,
    const void* __restrict__ log_A, const void* __restrict__ D_param,
    const float* __restrict__ carryH, const int* __restrict__ flagp)
{
    const bool f32 = (*flagp != 0);
    const int tid  = threadIdx.x;
    const int half = tid & 1;
    const int d    = blockIdx.x * DPB + (tid >> 1);
    const int c    = blockIdx.y, b = blockIdx.z;
    const float Dd = ldx(D_param, d, f32);
    float A_[8], h[8];
    const size_t ci = (((size_t)b * NC + c) * D_INNER + d) * D_STATE + half * 8;
    #pragma unroll
    for (int j = 0; j < 8; ++j) {
        A_[j] = -__expf(ldx(log_A, d * D_STATE + half * 8 + j, f32));
        h[j] = carryH[ci + j];
    }
    size_t tok = (size_t)b * LL + c * CL;
    for (int t = 0; t < CL; ++t, ++tok) {
        const float dl = bf2f(delta[tok * D_INNER + d]);
        const float ul = bf2f(us[tok * D_INNER + d]);
        const uint4 Bu = *(const uint4*)(xdbl + tok * 128 + DT_RANK + half * 8);
        const uint4 Cu = *(const uint4*)(xdbl + tok * 128 + DT_RANK + D_STATE + half * 8);
        const float dlul = dl * ul;
        const unsigned int bw[4] = {Bu.x, Bu.y, Bu.z, Bu.w};
        const unsigned int cw_[4] = {Cu.x, Cu.y, Cu.z, Cu.w};
        float p = 0.f;
        #pragma unroll
        for (int j = 0; j < 8; ++j) {
            const float Bn = (j & 1) ? bfu_hi(bw[j >> 1]) : bfu_lo(bw[j >> 1]);
            const float Cn = (j & 1) ? bfu_hi(cw_[j >> 1]) : bfu_lo(cw_[j >> 1]);
            const float a  = __expf(dl * A_[j]);
            h[j] = a * h[j] + dlul * Bn;
            p += h[j] * Cn;
        }
        p += __shfl_xor(p, 1, 64);          // combine the two n-halves
        if (half == 0) {
            const float vv = bf2f(uv[tok * (2*D_INNER) + D_INNER + d]);
            uv[tok * (2*D_INNER) + d] = f2bf((p + ul * Dd) * (vv / (1.f + __expf(-vv))));
        }
    }
}

extern "C" void kernel_launch(void* const* d_in, const int* in_sizes, int n_in,
                              void* d_out, int out_size, void* d_ws, size_t ws_size,
                              hipStream_t stream)
{
    const void* x      = d_in[0];
    const void* ln_g   = d_in[1];
    const void* ln_b   = d_in[2];
    const void* W_in   = d_in[3];
    const void* conv_w = d_in[4];
    const void* conv_b = d_in[5];
    const void* W_xp   = d_in[6];
    const void* W_dt   = d_in[7];
    const void* b_dt   = d_in[8];
    const void* log_A  = d_in[9];
    const void* D_par  = d_in[10];
    const void* W_out  = d_in[11];

    // workspace: [flag 512B][xn T*768 — carryA overlay after GEMM-uv]
    //            [uv T*3072][us T*1536][xdbl T*128][delta T*1536][carryH 6.29MB]
    // total 64.0 MB
    int* flag  = (int*)d_ws;
    u16* ws    = (u16*)((char*)d_ws + 512);
    u16* xn    = ws;
    u16* uv    = xn + (size_t)TT * D_MODEL;
    u16* us    = uv + (size_t)TT * 2 * D_INNER;
    u16* xdbl  = us + (size_t)TT * D_INNER;
    u16* delta = xdbl + (size_t)TT * 128;
    float* carryA = (float*)xn;                       // 2*32*1536*16*4B = 6.29MB = |xn|
    float* carryH = (float*)(delta + (size_t)TT * D_INNER);

    detect_kernel<<<1, 256, 0, stream>>>(x, flag);
    ln_kernel<<<TT, 256, 0, stream>>>(x, ln_g, ln_b, xn, flag);
    // uv = xn @ W_in  (4096x3072, K=768)  [128x128 tile, 768 blocks]
    mfma_gemm128<0><<<dim3(2 * D_INNER / 128, TT / 128), 256, 0, stream>>>(
        xn, W_in, uv, nullptr, flag, D_MODEL, D_MODEL, 2 * D_INNER, 2 * D_INNER);
    // us = silu(causal_conv(uv[:, :1536]))
    conv_silu_kernel<<<(TT * D_INNER) / 256, 256, 0, stream>>>(uv, conv_w, conv_b, us, flag);
    // xdbl = us @ W_xproj  (4096x128, K=1536)  [64x64 tile]
    mfma_gemm<0><<<dim3(128 / 64, TT / 64), 256, 0, stream>>>(
        us, W_xp, xdbl, nullptr, nullptr, flag, D_INNER, D_INNER, 128, 128);
    // delta = softplus(xdbl[:, :96] @ W_dt + b_dt)  (4096x1536, K=96)  [128x128 tile]
    mfma_gemm128<1><<<dim3(D_INNER / 128, TT / 128), 256, 0, stream>>>(
        xdbl, W_dt, delta, b_dt, flag, DT_RANK, 128, D_INNER, D_INNER);
    // chunked selective scan (NC=32 -> 12 waves/CU)
    scan1_kernel<<<dim3(D_INNER / DPB, NC, BB), 256, 0, stream>>>(
        delta, us, xdbl, log_A, carryA, carryH, flag);
    scan2_kernel<<<(BB * D_INNER * D_STATE) / 256, 256, 0, stream>>>(carryA, carryH);
    scan3_kernel<<<dim3(D_INNER / DPB, NC, BB), 256, 0, stream>>>(
        delta, us, xdbl, uv, log_A, D_par, carryH, flag);
    // out = y @ W_out + x  (4096x768, K=1536)  [64x64 tile, 768 blocks]
    mfma_gemm<2><<<dim3(D_MODEL / 64, TT / 64), 256, 0, stream>>>(
        uv, W_out, nullptr, d_out, x, flag, D_INNER, 2 * D_INNER, D_MODEL, D_MODEL);
}

// Round 8
// 394.453 us; speedup vs baseline: 5.4517x; 1.1509x over previous
//
#include <hip/hip_runtime.h>

#define D_MODEL 768
#define D_INNER 1536
#define D_STATE 16
#define DT_RANK 96
#define BB 2
#define LL 2048
#define TT (BB*LL)          // 4096 tokens
#define NC 32               // chunks per sequence
#define CL 64               // chunk length
#define DPB 128             // d's per scan block
#define SKK 4               // split-K factor for xdbl GEMM

typedef unsigned short u16;
typedef short bf16x8 __attribute__((ext_vector_type(8)));
typedef unsigned short u16x8 __attribute__((ext_vector_type(8)));
typedef float f32x4  __attribute__((ext_vector_type(4)));

__device__ __forceinline__ float bf2f(u16 u) {
    union { unsigned int i; float f; } c; c.i = ((unsigned int)u) << 16; return c.f;
}
__device__ __forceinline__ u16 f2bf(float f) {
    union { float f; unsigned int i; } c; c.f = f;
    unsigned int x = c.i;
    return (u16)((x + 0x7fffu + ((x >> 16) & 1u)) >> 16);   // RNE
}
__device__ __forceinline__ float bfu_lo(unsigned int u) {
    union { unsigned int i; float f; } c; c.i = u << 16; return c.f;
}
__device__ __forceinline__ float bfu_hi(unsigned int u) {
    union { unsigned int i; float f; } c; c.i = u & 0xFFFF0000u; return c.f;
}
__device__ __forceinline__ float ldx(const void* p, size_t i, bool f32) {
    return f32 ? ((const float*)p)[i] : bf2f(((const u16*)p)[i]);
}

// ---- dtype detect: if buffer is fp32, even-index u16s are mantissa-low garbage ----
__global__ void detect_kernel(const void* x, int* flag)
{
    __shared__ int bad;
    if (threadIdx.x == 0) bad = 0;
    __syncthreads();
    const u16* p = (const u16*)x;
    int local = 0;
    for (int i = threadIdx.x; i < 2048; i += 256) {
        const float v = bf2f(p[2 * i]);
        if (!(fabsf(v) < 1e4f)) local = 1;
    }
    if (local) atomicOr(&bad, 1);
    __syncthreads();
    if (threadIdx.x == 0) *flag = bad;       // 1 => inputs are fp32
}

// ---- weight transpose: src (K x N, flex) -> dst (N x K, bf16), 64x64 LDS tiles ----
__global__ __launch_bounds__(256) void transpose_kernel(
    const void* __restrict__ src, u16* __restrict__ dst,
    int K, int N, const int* __restrict__ flagp)
{
    const bool f32 = (*flagp != 0);
    __shared__ u16 tile[64][72];
    const int t  = threadIdx.x;
    const int n0 = blockIdx.x * 64, k0 = blockIdx.y * 64;
    {
        const int r = t >> 2, c = (t & 3) * 16;     // tile-local (k, n)
        const int k = k0 + r;
        if (k < K) {
            #pragma unroll
            for (int i = 0; i < 16; ++i)
                tile[r][c + i] = f2bf(ldx(src, (size_t)k * N + n0 + c + i, f32));
        }
    }
    __syncthreads();
    {
        const int nl = t >> 2, kl = (t & 3) * 16;   // tile-local (n, k)
        const int n = n0 + nl;
        #pragma unroll
        for (int i = 0; i < 16; ++i) {
            const int k = k0 + kl + i;
            if (k < K) dst[(size_t)n * K + k] = tile[kl + i][nl];
        }
    }
}

// ---------------- LayerNorm: x (T,768) -> xn (T,768) bf16 ----------------
__global__ __launch_bounds__(256) void ln_kernel(const void* __restrict__ x,
    const void* __restrict__ g, const void* __restrict__ b, u16* __restrict__ xn,
    const int* __restrict__ flagp)
{
    const bool f32 = (*flagp != 0);
    const int tok = blockIdx.x;
    const int tid = threadIdx.x;
    const size_t base = (size_t)tok * D_MODEL;
    float v[3];
    v[0] = ldx(x, base + tid, f32);
    v[1] = ldx(x, base + tid + 256, f32);
    v[2] = ldx(x, base + tid + 512, f32);
    float s = v[0] + v[1] + v[2];
    float q = v[0]*v[0] + v[1]*v[1] + v[2]*v[2];
    #pragma unroll
    for (int o = 32; o > 0; o >>= 1) {
        s += __shfl_down(s, o, 64);
        q += __shfl_down(q, o, 64);
    }
    __shared__ float ss[4], qq[4];
    if ((tid & 63) == 0) { ss[tid >> 6] = s; qq[tid >> 6] = q; }
    __syncthreads();
    const float S = ss[0] + ss[1] + ss[2] + ss[3];
    const float Q = qq[0] + qq[1] + qq[2] + qq[3];
    const float mu  = S * (1.f / D_MODEL);
    const float var = Q * (1.f / D_MODEL) - mu * mu;
    const float rs  = rsqrtf(var + 1e-5f);
    u16* outr = xn + base;
    #pragma unroll
    for (int i = 0; i < 3; ++i) {
        const int c = tid + i * 256;
        outr[c] = f2bf((v[i] - mu) * rs * ldx(g, c, f32) + ldx(b, c, f32));
    }
}

// ------- MFMA GEMM 64x64 tile, BK=32, 4 waves; A (M,K) bf16, Bt (N,K) bf16 -------
// EPI 0: bf16 store. EPI 2: + res[idx] (flex), flex store. EPI 3: atomicAdd fp32 (split-K).
#define SA 40
template<int EPI>
__global__ __launch_bounds__(256) void mfma_gemm(
    const u16* __restrict__ A, const u16* __restrict__ Bt,
    u16* __restrict__ C, void* __restrict__ Cout, const void* __restrict__ aux,
    float* __restrict__ Cf, const int* __restrict__ flagp,
    int Kslice, int lda, int ldbt, int ldc)
{
    const bool f32 = (*flagp != 0);
    __shared__ u16 As[64 * SA];
    __shared__ u16 Bs[64 * SA];
    const int tid  = threadIdx.x;
    const int wave = tid >> 6, lane = tid & 63;
    const int lrow = lane & 15, quad = lane >> 4;
    const int row0 = blockIdx.y * 64, col0 = blockIdx.x * 64;
    const int k0   = blockIdx.z * Kslice;
    const int sr = tid >> 2, sk = (tid & 3) * 8;    // staging: (row, k-chunk)
    f32x4 acc[4] = {{0.f,0.f,0.f,0.f},{0.f,0.f,0.f,0.f},{0.f,0.f,0.f,0.f},{0.f,0.f,0.f,0.f}};
    for (int kt = k0; kt < k0 + Kslice; kt += 32) {
        *(u16x8*)(&As[sr * SA + sk]) = *(const u16x8*)(A  + (size_t)(row0 + sr) * lda  + kt + sk);
        *(u16x8*)(&Bs[sr * SA + sk]) = *(const u16x8*)(Bt + (size_t)(col0 + sr) * ldbt + kt + sk);
        __syncthreads();
        const bf16x8 af = *(const bf16x8*)(&As[(wave * 16 + lrow) * SA + quad * 8]);
        #pragma unroll
        for (int t = 0; t < 4; ++t) {
            const bf16x8 bf_ = *(const bf16x8*)(&Bs[(t * 16 + lrow) * SA + quad * 8]);
            acc[t] = __builtin_amdgcn_mfma_f32_16x16x32_bf16(af, bf_, acc[t], 0, 0, 0);
        }
        __syncthreads();
    }
    #pragma unroll
    for (int t = 0; t < 4; ++t) {
        #pragma unroll
        for (int r = 0; r < 4; ++r) {
            const int row = row0 + wave * 16 + quad * 4 + r;   // C/D: row=quad*4+reg
            const int col = col0 + t * 16 + lrow;              //      col=lane&15
            const size_t idx = (size_t)row * ldc + col;
            float vv = acc[t][r];
            if (EPI == 2) {
                vv += ldx(aux, idx, f32);
                if (f32) ((float*)Cout)[idx] = vv;
                else     ((u16*)Cout)[idx]   = f2bf(vv);
            } else if (EPI == 3) {
                atomicAdd(&Cf[idx], vv);
            } else {
                C[idx] = f2bf(vv);
            }
        }
    }
}

// ------- MFMA GEMM 128x128 tile, BK=32, 4 waves (2x2); A (M,K), Bt (N,K) bf16 -------
// EPI 0: bf16 store. EPI 1: softplus(acc + bias[col]) bf16 store.
template<int EPI>
__global__ __launch_bounds__(256) void mfma_gemm128(
    const u16* __restrict__ A, const u16* __restrict__ Bt,
    u16* __restrict__ C, const void* __restrict__ aux,
    const int* __restrict__ flagp,
    int K, int lda, int ldbt, int ldc)
{
    const bool f32 = (*flagp != 0);
    __shared__ u16 As[128 * SA];
    __shared__ u16 Bs[128 * SA];
    const int tid  = threadIdx.x;
    const int wave = tid >> 6, lane = tid & 63;
    const int lrow = lane & 15, quad = lane >> 4;
    const int wy = wave >> 1, wx = wave & 1;
    const int row0 = blockIdx.y * 128, col0 = blockIdx.x * 128;
    const int sr = tid >> 1, sk = (tid & 1) * 16;   // staging: (row, k-half)
    f32x4 acc[4][4];
    #pragma unroll
    for (int i = 0; i < 4; ++i)
        #pragma unroll
        for (int j = 0; j < 4; ++j) acc[i][j] = (f32x4){0.f,0.f,0.f,0.f};
    for (int kt = 0; kt < K; kt += 32) {
        *(u16x8*)(&As[sr * SA + sk])     = *(const u16x8*)(A  + (size_t)(row0 + sr) * lda  + kt + sk);
        *(u16x8*)(&As[sr * SA + sk + 8]) = *(const u16x8*)(A  + (size_t)(row0 + sr) * lda  + kt + sk + 8);
        *(u16x8*)(&Bs[sr * SA + sk])     = *(const u16x8*)(Bt + (size_t)(col0 + sr) * ldbt + kt + sk);
        *(u16x8*)(&Bs[sr * SA + sk + 8]) = *(const u16x8*)(Bt + (size_t)(col0 + sr) * ldbt + kt + sk + 8);
        __syncthreads();
        bf16x8 af[4], bf_[4];
        #pragma unroll
        for (int i = 0; i < 4; ++i)
            af[i] = *(const bf16x8*)(&As[(wy * 64 + i * 16 + lrow) * SA + quad * 8]);
        #pragma unroll
        for (int j = 0; j < 4; ++j)
            bf_[j] = *(const bf16x8*)(&Bs[(wx * 64 + j * 16 + lrow) * SA + quad * 8]);
        #pragma unroll
        for (int i = 0; i < 4; ++i)
            #pragma unroll
            for (int j = 0; j < 4; ++j)
                acc[i][j] = __builtin_amdgcn_mfma_f32_16x16x32_bf16(af[i], bf_[j], acc[i][j], 0, 0, 0);
        __syncthreads();
    }
    #pragma unroll
    for (int i = 0; i < 4; ++i) {
        #pragma unroll
        for (int j = 0; j < 4; ++j) {
            #pragma unroll
            for (int r = 0; r < 4; ++r) {
                const int row = row0 + wy * 64 + i * 16 + quad * 4 + r;
                const int col = col0 + wx * 64 + j * 16 + lrow;
                const size_t idx = (size_t)row * ldc + col;
                float vv = acc[i][j][r];
                if (EPI == 1) {
                    vv += ldx(aux, col, f32);
                    vv = (vv > 20.f) ? vv : log1pf(__expf(vv));
                }
                C[idx] = f2bf(vv);
            }
        }
    }
}

// -------- split-K finalize: xdbl = bf16(xdblF) --------
__global__ __launch_bounds__(256) void convert_kernel(const float* __restrict__ src,
                                                      u16* __restrict__ dst, int n)
{
    const int i = blockIdx.x * 256 + threadIdx.x;
    if (i < n) dst[i] = f2bf(src[i]);
}

// ---- causal depthwise conv (width 4, left-pad 3) + SiLU: uv[:, :1536] -> us ----
__global__ __launch_bounds__(256) void conv_silu_kernel(
    const u16* __restrict__ uv, const void* __restrict__ cw, const void* __restrict__ cb,
    u16* __restrict__ us, const int* __restrict__ flagp)
{
    const bool f32 = (*flagp != 0);
    const int idx = blockIdx.x * 256 + threadIdx.x;
    const int d   = idx % D_INNER;
    const int tok = idx / D_INNER;
    const int l   = tok & (LL - 1);
    float acc = ldx(cb, d, f32);
    #pragma unroll
    for (int j = 0; j < 4; ++j) {
        const int li = l - 3 + j;
        if (li >= 0)
            acc += bf2f(uv[(size_t)(tok - 3 + j) * (2*D_INNER) + d]) * ldx(cw, d * 4 + j, f32);
    }
    us[idx] = f2bf(acc / (1.f + __expf(-acc)));
}

// ----- scan pass 1: per-chunk local scan -> carries (prod a, h_local_end) -----
__global__ __launch_bounds__(256) void scan1_kernel(
    const u16* __restrict__ delta, const u16* __restrict__ us,
    const u16* __restrict__ xdbl, const void* __restrict__ log_A,
    float* __restrict__ carryA, float* __restrict__ carryH,
    const int* __restrict__ flagp)
{
    const bool f32 = (*flagp != 0);
    const int tid  = threadIdx.x;
    const int half = tid & 1;
    const int d    = blockIdx.x * DPB + (tid >> 1);
    const int c    = blockIdx.y, b = blockIdx.z;
    float A_[8], h[8];
    #pragma unroll
    for (int j = 0; j < 8; ++j) {
        A_[j] = -__expf(ldx(log_A, d * D_STATE + half * 8 + j, f32));
        h[j] = 0.f;
    }
    float sdl = 0.f;
    size_t tok = (size_t)b * LL + c * CL;
    for (int t = 0; t < CL; ++t, ++tok) {
        const float dl = bf2f(delta[tok * D_INNER + d]);
        const float ul = bf2f(us[tok * D_INNER + d]);
        const uint4 Bu = *(const uint4*)(xdbl + tok * 128 + DT_RANK + half * 8);
        const float dlul = dl * ul;
        sdl += dl;
        const unsigned int bw[4] = {Bu.x, Bu.y, Bu.z, Bu.w};
        #pragma unroll
        for (int j = 0; j < 8; ++j) {
            const float Bn = (j & 1) ? bfu_hi(bw[j >> 1]) : bfu_lo(bw[j >> 1]);
            const float a  = __expf(dl * A_[j]);
            h[j] = a * h[j] + dlul * Bn;
        }
    }
    const size_t ci = (((size_t)b * NC + c) * D_INNER + d) * D_STATE + half * 8;
    #pragma unroll
    for (int j = 0; j < 8; ++j) {
        carryA[ci + j] = __expf(A_[j] * sdl);
        carryH[ci + j] = h[j];
    }
}

// -------- scan pass 2: exclusive scan over chunk carries, in place on carryH --------
__global__ __launch_bounds__(256) void scan2_kernel(
    const float* __restrict__ carryA, float* __restrict__ carryH)
{
    const int gid = blockIdx.x * 256 + threadIdx.x;
    const int b   = gid / (D_INNER * D_STATE);
    const int dn  = gid % (D_INNER * D_STATE);
    float hrun = 0.f;
    #pragma unroll
    for (int c = 0; c < NC; ++c) {
        const size_t ci = ((size_t)(b * NC + c) * D_INNER * D_STATE) + dn;
        const float a = carryA[ci], hh = carryH[ci];
        carryH[ci] = hrun;
        hrun = a * hrun + hh;
    }
}

// ------ scan pass 3: re-run chunk seeded with carry; emit y = gated output ------
__global__ __launch_bounds__(256) void scan3_kernel(
    const u16* __restrict__ delta, const u16* __restrict__ us,
    const u16* __restrict__ xdbl, u16* __restrict__ uv,
    const void* __restrict__ log_A, const void* __restrict__ D_param,
    const float* __restrict__ carryH, const int* __restrict__ flagp)
{
    const bool f32 = (*flagp != 0);
    const int tid  = threadIdx.x;
    const int half = tid & 1;
    const int d    = blockIdx.x * DPB + (tid >> 1);
    const int c    = blockIdx.y, b = blockIdx.z;
    const float Dd = ldx(D_param, d, f32);
    float A_[8], h[8];
    const size_t ci = (((size_t)b * NC + c) * D_INNER + d) * D_STATE + half * 8;
    #pragma unroll
    for (int j = 0; j < 8; ++j) {
        A_[j] = -__expf(ldx(log_A, d * D_STATE + half * 8 + j, f32));
        h[j] = carryH[ci + j];
    }
    size_t tok = (size_t)b * LL + c * CL;
    for (int t = 0; t < CL; ++t, ++tok) {
        const float dl = bf2f(delta[tok * D_INNER + d]);
        const float ul = bf2f(us[tok * D_INNER + d]);
        const uint4 Bu = *(const uint4*)(xdbl + tok * 128 + DT_RANK + half * 8);
        const uint4 Cu = *(const uint4*)(xdbl + tok * 128 + DT_RANK + D_STATE + half * 8);
        const float dlul = dl * ul;
        const unsigned int bw[4] = {Bu.x, Bu.y, Bu.z, Bu.w};
        const unsigned int cw_[4] = {Cu.x, Cu.y, Cu.z, Cu.w};
        float p = 0.f;
        #pragma unroll
        for (int j = 0; j < 8; ++j) {
            const float Bn = (j & 1) ? bfu_hi(bw[j >> 1]) : bfu_lo(bw[j >> 1]);
            const float Cn = (j & 1) ? bfu_hi(cw_[j >> 1]) : bfu_lo(cw_[j >> 1]);
            const float a  = __expf(dl * A_[j]);
            h[j] = a * h[j] + dlul * Bn;
            p += h[j] * Cn;
        }
        p += __shfl_xor(p, 1, 64);
        if (half == 0) {
            const float vv = bf2f(uv[tok * (2*D_INNER) + D_INNER + d]);
            uv[tok * (2*D_INNER) + d] = f2bf((p + ul * Dd) * (vv / (1.f + __expf(-vv))));
        }
    }
}

extern "C" void kernel_launch(void* const* d_in, const int* in_sizes, int n_in,
                              void* d_out, int out_size, void* d_ws, size_t ws_size,
                              hipStream_t stream)
{
    const void* x      = d_in[0];
    const void* ln_g   = d_in[1];
    const void* ln_b   = d_in[2];
    const void* W_in   = d_in[3];
    const void* conv_w = d_in[4];
    const void* conv_b = d_in[5];
    const void* W_xp   = d_in[6];
    const void* W_dt   = d_in[7];
    const void* b_dt   = d_in[8];
    const void* log_A  = d_in[9];
    const void* D_par  = d_in[10];
    const void* W_out  = d_in[11];

    // workspace (~74 MB): flag | xn (carryA overlay) | uv | us | xdbl | delta |
    //                     carryH | WtIn | WtXp | WtDt | WtOut | xdblF (fp32)
    int* flag  = (int*)d_ws;
    u16* ws    = (u16*)((char*)d_ws + 512);
    u16* xn    = ws;
    u16* uv    = xn + (size_t)TT * D_MODEL;
    u16* us    = uv + (size_t)TT * 2 * D_INNER;
    u16* xdbl  = us + (size_t)TT * D_INNER;
    u16* delta = xdbl + (size_t)TT * 128;
    float* carryA = (float*)xn;                       // overlays xn after uv-GEMM
    float* carryH = (float*)(delta + (size_t)TT * D_INNER);
    u16* WtIn  = (u16*)(carryH + (size_t)BB * NC * D_INNER * D_STATE);
    u16* WtXp  = WtIn  + (size_t)2 * D_INNER * D_MODEL;    // 3072 x 768
    u16* WtDt  = WtXp  + (size_t)(DT_RANK + 2 * D_STATE) * D_INNER;  // 128 x 1536
    u16* WtOut = WtDt  + (size_t)D_INNER * DT_RANK;        // 1536 x 96
    float* xdblF = (float*)(WtOut + (size_t)D_MODEL * D_INNER);      // 768 x 1536 then fp32 scratch

    detect_kernel<<<1, 256, 0, stream>>>(x, flag);
    // transpose weights -> N x K bf16
    transpose_kernel<<<dim3(2 * D_INNER / 64, D_MODEL / 64), 256, 0, stream>>>(
        W_in, WtIn, D_MODEL, 2 * D_INNER, flag);
    transpose_kernel<<<dim3(2, D_INNER / 64), 256, 0, stream>>>(
        W_xp, WtXp, D_INNER, 128, flag);
    transpose_kernel<<<dim3(D_INNER / 64, 2), 256, 0, stream>>>(
        W_dt, WtDt, DT_RANK, D_INNER, flag);
    transpose_kernel<<<dim3(D_MODEL / 64, D_INNER / 64), 256, 0, stream>>>(
        W_out, WtOut, D_INNER, D_MODEL, flag);
    hipMemsetAsync(xdblF, 0, (size_t)TT * 128 * sizeof(float), stream);

    ln_kernel<<<TT, 256, 0, stream>>>(x, ln_g, ln_b, xn, flag);
    // uv = xn @ W_in  (4096x3072, K=768)  [128x128, 768 blocks]
    mfma_gemm128<0><<<dim3(2 * D_INNER / 128, TT / 128), 256, 0, stream>>>(
        xn, WtIn, uv, nullptr, flag, D_MODEL, D_MODEL, D_MODEL, 2 * D_INNER);
    // us = silu(causal_conv(uv[:, :1536]))
    conv_silu_kernel<<<(TT * D_INNER) / 256, 256, 0, stream>>>(uv, conv_w, conv_b, us, flag);
    // xdbl = us @ W_xproj  (4096x128, K=1536)  [64x64, split-K x4 -> 512 blocks]
    mfma_gemm<3><<<dim3(2, TT / 64, SKK), 256, 0, stream>>>(
        us, WtXp, nullptr, nullptr, nullptr, xdblF, flag,
        D_INNER / SKK, D_INNER, D_INNER, 128);
    convert_kernel<<<(TT * 128 + 255) / 256, 256, 0, stream>>>(xdblF, xdbl, TT * 128);
    // delta = softplus(xdbl[:, :96] @ W_dt + b_dt)  (4096x1536, K=96)  [128x128]
    mfma_gemm128<1><<<dim3(D_INNER / 128, TT / 128), 256, 0, stream>>>(
        xdbl, WtDt, delta, b_dt, flag, DT_RANK, 128, DT_RANK, D_INNER);
    // chunked selective scan
    scan1_kernel<<<dim3(D_INNER / DPB, NC, BB), 256, 0, stream>>>(
        delta, us, xdbl, log_A, carryA, carryH, flag);
    scan2_kernel<<<(BB * D_INNER * D_STATE) / 256, 256, 0, stream>>>(carryA, carryH);
    scan3_kernel<<<dim3(D_INNER / DPB, NC, BB), 256, 0, stream>>>(
        delta, us, xdbl, uv, log_A, D_par, carryH, flag);
    // out = y @ W_out + x  (4096x768, K=1536)  [64x64, 768 blocks]
    mfma_gemm<2><<<dim3(D_MODEL / 64, TT / 64, 1), 256, 0, stream>>>(
        uv, WtOut, nullptr, d_out, x, nullptr, flag,
        D_INNER, 2 * D_INNER, D_INNER, D_MODEL);
}